// Round 5
// baseline (5068.265 us; speedup 1.0000x reference)
//
#include <hip/hip_runtime.h>
#include <hip/hip_bf16.h>
#include <cstdint>
#include <cstddef>

#define NDIMC   128
#define DEPTHC  6
#define NPASSESC 4
#define NNODES  50000
#define NEDGES  800000
#define NODEIN  5
#define LNEPS   1e-5f

// ---------------------------------------------------------------------------
// ws layout (bytes) — ~224 MiB, below proven-safe 256,000,004
#define H_OFF    0ull                     // h:  50000*128*4  = 25.6 MB fp32
#define E_OFF    25600000ull              // e:  800000*128*2 = 204.8 MB bf16 (CSR-slot order)
#define PW_OFF   230400000ull             // packed weights: 4 * 196,608 B bf16
#define FLAG_OFF 231186432ull
#define DEG_OFF  231186436ull             // 50001 int
#define RS_OFF   231386440ull             // rowstart: 50001 int
#define CUR_OFF  231586444ull             // cursor:   50000 int
#define EIDX_OFF 231786444ull             // eidx:     800000 int -> ends 234,986,444
#define PWMAT    98304                    // shorts per packed matrix (6*4*4096)

typedef __attribute__((ext_vector_type(8))) short mgn_sh8;
typedef __attribute__((ext_vector_type(4))) float mgn_f32x4;

// ---------------------------------------------------------------------------
__device__ __forceinline__ unsigned mgn_bf16bits(float f) {
    unsigned x = __float_as_uint(f);
    return (x + 0x7fffu + ((x >> 16) & 1u)) >> 16;   // RNE
}
__device__ __forceinline__ unsigned mgn_pk(float a, float b) {
    __hip_bfloat162 t = __float22bfloat162_rn(make_float2(a, b));
    union { __hip_bfloat162 h; unsigned u; } c; c.h = t; return c.u;
}

// xl index with XOR swizzle: row stride 128 shorts (256 B), swizzle flips
// byte bits 4..6 by row&7 -> A-frag reads 2-way max (free), stash b64 spread.
// All xl accesses are multiples of 8 shorts (16 B) or +4 within a block, so
// the swizzle commutes with every access width used.
__device__ __forceinline__ int mgn_xli(int row, int colsh) {
    return row * 128 + (colsh ^ ((row & 7) << 3));
}

// DPP-based partial butterfly (VALU, off the LDS pipe).
// 0xB1 = quad_perm [1,0,3,2] = lane^1; 0x4E = quad_perm [2,3,0,1] = lane^2;
// 0x128 = row_ror:8 = lane^8 within each 16-lane row.
template <int CTRL>
__device__ __forceinline__ float mgn_dppadd(float x) {
    int y = __builtin_amdgcn_update_dpp(0, __float_as_int(x), CTRL, 0xF, 0xF, true);
    return x + __int_as_float(y);
}

// async 16B global->LDS DMA (no VGPR round-trip; tracked by vmcnt)
__device__ __forceinline__ void mgn_cp16(const unsigned short* g, unsigned short* l) {
    __builtin_amdgcn_global_load_lds(
        (const __attribute__((address_space(1))) void*)g,
        (__attribute__((address_space(3))) void*)l, 16, 0, 0);
}
// Stage one 8 KB weight QUARTER (4096 shorts = 8 chunks of 512) with BW waves.
template <int BW>
__device__ __forceinline__ void mgn_stage_q(const unsigned short* __restrict__ src,
                                            unsigned short* wbuf, int tid) {
    const int w = tid >> 6, l = tid & 63;
#pragma unroll
    for (int i = 0; i < 8 / BW; ++i) {
        const int off = (w * (8 / BW) + i) * 512 + l * 8;   // shorts
        mgn_cp16(src + off, wbuf + off);
    }
}

// One weight-quarter of MFMAs: 4 t'-groups x 2 sp, both row-tiles, ONE N-half.
// a0p/a1p point at the K-half's A-frag pair. acc = 4 per row-tile (N-half).
// Wrapped in s_setprio(1) by callers' cluster (T5).
__device__ __forceinline__ void mgn_qcompN(const unsigned short* __restrict__ buf, int l,
                                           const mgn_sh8* a0p, const mgn_sh8* a1p,
                                           mgn_f32x4* acc0, mgn_f32x4* acc1) {
    __builtin_amdgcn_s_setprio(1);
#pragma unroll
    for (int t = 0; t < 4; ++t)
#pragma unroll
        for (int sp = 0; sp < 2; ++sp) {
            mgn_sh8 b = *(const mgn_sh8*)&buf[(t * 2 + sp) * 512 + l * 8];
            acc0[t] = __builtin_amdgcn_mfma_f32_16x16x32_bf16(a0p[sp], b, acc0[t], 0, 0, 0);
            acc1[t] = __builtin_amdgcn_mfma_f32_16x16x32_bf16(a1p[sp], b, acc1[t], 0, 0, 0);
        }
    __builtin_amdgcn_s_setprio(0);
}

// ---------------------------------------------------------------------------
// flag = 1 -> ij is int32, flag = 0 -> ij is int64
__global__ void mgn_detect_kernel(const int* __restrict__ ij, int* __restrict__ flag) {
    __shared__ int any;
    if (threadIdx.x == 0) any = 0;
    __syncthreads();
    if (ij[2 * threadIdx.x + 1] != 0) atomicOr(&any, 1);
    __syncthreads();
    if (threadIdx.x == 0) *flag = any;
}

__device__ __forceinline__ long mgn_load_idx(const int* __restrict__ ij, long pos, int is32) {
    if (is32) return (long)ij[pos];
    const long long* ij8 = (const long long*)ij;
    return (long)ij8[pos];
}

// ---------------------------------------------------------------------------
// Pack fp32 row-major W[d][k][n] into QUARTER-streamed MFMA B-frag order.
// Quarter qd = nh*2 + sh  (nh = N-half, sh = K-half) is a contiguous 8 KB
// block, in the exact order the N-split schedule consumes them:
//   qd0=(nh0,h0) qd1=(nh0,h1) qd2=(nh1,h0) qd3=(nh1,h1)
// i = ((((d*4+qd)*4+t')*2+sp)*64+lane)*8+j holds
//   W[d][(sh*2+sp)*32 + (lane>>4)*8 + j][(lane&15)*8 + nh*4 + t']
__global__ void mgn_pack_kernel(const float* __restrict__ W, unsigned short* __restrict__ pw) {
    int i = blockIdx.x * blockDim.x + threadIdx.x;
    if (i >= PWMAT) return;
    int j    = i & 7;
    int lane = (i >> 3) & 63;
    int sp   = (i >> 9) & 1;
    int tp   = (i >> 10) & 3;
    int qd   = (i >> 12) & 3;
    int d    = i >> 14;
    int sh = qd & 1, nh = qd >> 1;
    int k = (sh * 2 + sp) * 32 + (lane >> 4) * 8 + j;
    int n = (lane & 15) * 8 + nh * 4 + tp;
    pw[i] = (unsigned short)mgn_bf16bits(W[(d * NDIMC + k) * NDIMC + n]);
}

// ---------------------------------------------------------------------------
// CSR build: histogram -> scan -> fill
__global__ void mgn_deg_kernel(const int* __restrict__ ij, const int* __restrict__ flag,
                               int* __restrict__ deg) {
    int e = blockIdx.x * blockDim.x + threadIdx.x;
    if (e >= NEDGES) return;
    int dst = (int)mgn_load_idx(ij, (long)NEDGES + e, *flag);
    atomicAdd(&deg[dst], 1);
}

__global__ void mgn_scan_kernel(const int* __restrict__ deg,
                                int* __restrict__ rowstart, int* __restrict__ cursor) {
    __shared__ int partial[256];
    const int tid = threadIdx.x;
    const int CH = (NNODES + 255) / 256;   // 196
    const int base = tid * CH;
    int s = 0;
    for (int i = 0; i < CH; ++i) {
        int idx = base + i;
        if (idx < NNODES) s += deg[idx];
    }
    partial[tid] = s;
    __syncthreads();
    for (int off = 1; off < 256; off <<= 1) {
        int add = (tid >= off) ? partial[tid - off] : 0;
        __syncthreads();
        partial[tid] += add;
        __syncthreads();
    }
    int run = (tid == 0) ? 0 : partial[tid - 1];
    for (int i = 0; i < CH; ++i) {
        int idx = base + i;
        if (idx < NNODES) {
            rowstart[idx] = run;
            cursor[idx]   = run;
            run += deg[idx];
        }
    }
    if (tid == 255) rowstart[NNODES] = run;
}

__global__ void mgn_fill_kernel(const int* __restrict__ ij, const int* __restrict__ flag,
                                int* __restrict__ cursor, int* __restrict__ eidx) {
    int e = blockIdx.x * blockDim.x + threadIdx.x;
    if (e >= NEDGES) return;
    int dst = (int)mgn_load_idx(ij, (long)NEDGES + e, *flag);
    int pos = atomicAdd(&cursor[dst], 1);
    eidx[pos] = e;
}

// ---------------------------------------------------------------------------
__global__ void mgn_encoder_kernel(const float* __restrict__ v,
                                   const float* __restrict__ encW,
                                   const float* __restrict__ encB,
                                   float* __restrict__ h) {
    int idx = blockIdx.x * blockDim.x + threadIdx.x;
    if (idx >= NNODES * NDIMC) return;
    int n = idx >> 7, d = idx & 127;
    float acc = encB[d];
#pragma unroll
    for (int k = 0; k < NODEIN; ++k)
        acc = fmaf(v[n * NODEIN + k], encW[k * NDIMC + d], acc);
    h[idx] = acc;
}

__global__ void mgn_decoder_kernel(const float* __restrict__ h,
                                   const float* __restrict__ decW,
                                   const float* __restrict__ decB,
                                   float* __restrict__ out) {
    int idx = blockIdx.x * blockDim.x + threadIdx.x;
    if (idx >= NNODES * NODEIN) return;
    int n = idx / NODEIN, j = idx % NODEIN;
    float acc = decB[j];
#pragma unroll 8
    for (int k = 0; k < NDIMC; ++k)
        acc = fmaf(h[n * NDIMC + k], decW[k * NODEIN + j], acc);
    out[idx] = acc;
}

// ---------------------------------------------------------------------------
// Fused 6-deep residual MLP, bf16 MFMA core, fp32 residual/LN.
// r21: LDS-pipe reduction package on the r20 structure (best known, passed).
// r20 post-mortem: LDS data pipe ~60% busy is the top consumer (B 27%, shfl
// 14%, stash 11%, A 11%, conflicts 6%); nothing else saturated.
//  1. xl XOR-swizzled @ stride 128 (conflict patterns from stride-136 b64
//     stashes killed; LDS 51.2 -> 48 KB, still 3 blocks/CU)
//  2. LN reduce: xor1/xor2 via DPP quad_perm, xor8 via row_ror:8 (VALU, off
//     the LDS pipe); only xor4 remains a shuffle
//  3. h2-nh0 kept in 16 packed-bf16 regs (no LN stash round-trip)
//  4. s_setprio(1) around MFMA clusters (T5)
// Geometry unchanged: M=32/wave, N-split GEMMs, 8 KB quarter ping-pong,
// 8 phases/depth, 3 blocks/CU, no spills (live ~148 <= 170).
template <int MODE, int BW>
__global__ __launch_bounds__(BW * 64, 3) void mgn_mlp6_mfma_kernel(
    float* __restrict__ Xf,               // node: h
    unsigned short* __restrict__ Eb,      // e buffer (CSR-slot order)
    const float* __restrict__ H,          // edge: h for gather
    const int* __restrict__ ij,
    const int* __restrict__ flag,
    const int* __restrict__ rowstart,     // node CSR
    const int* __restrict__ eidx,         // edge: slot -> original edge id
    int addE, int nrows,
    const unsigned short* __restrict__ PW1,
    const unsigned short* __restrict__ PW2,
    const float* __restrict__ B1, const float* __restrict__ B2,
    const float* __restrict__ G,  const float* __restrict__ BT)
{
    __shared__ unsigned short xl[BW * 32 * 128];   // x/h1 tile, stride 128, XOR-swizzled (32 KB)
    __shared__ unsigned short wqA[4096];           // weight quarter ping (8 KB)
    __shared__ unsigned short wqB[4096];           // weight quarter pong (8 KB)
    const int tid = threadIdx.x;
    const int w   = tid >> 6;
    const int l   = tid & 63;
    const int q   = l >> 4;
    const int lm  = l & 15;
    const int ct  = lm * 8;                        // first of lane's 8 cols
    const int wbase = w * 32;                      // wave's first local row
    const long rowbase = (long)blockIdx.x * (32 * BW);

    const int is32 = (MODE == 1) ? *flag : 0;

    // pre-stage depth-0 W1 quarter 0 -> wqA; drains at first barrier
    mgn_stage_q<BW>(PW1, wqA, tid);

    // ---- tile load: xres fp32 regs (C layout) + LDS bf16 (A source)
    // lane owns 8 rows: row-tile u = rr>>2, r = rr&3
    float xres[8][8];
#pragma unroll
    for (int rr = 0; rr < 8; ++rr) {
        const int rloc = wbase + (rr >> 2) * 16 + q * 4 + (rr & 3);
        long gr = rowbase + rloc;
        bool ok = gr < nrows;
        float xv[8];
#pragma unroll
        for (int t = 0; t < 8; ++t) xv[t] = 0.f;
        if (MODE == 1) {
            if (ok) {
                long er = (long)eidx[gr];     // original edge id for this slot
                long i0 = mgn_load_idx(ij, er, is32);
                long i1 = mgn_load_idx(ij, (long)NEDGES + er, is32);
                const float* p0 = H + i0 * NDIMC + ct;
                const float* p1 = H + i1 * NDIMC + ct;
                float4 a0 = *(const float4*)p0, a1 = *(const float4*)(p0 + 4);
                float4 b0 = *(const float4*)p1, b1 = *(const float4*)(p1 + 4);
                xv[0] = a0.x - b0.x; xv[1] = a0.y - b0.y;
                xv[2] = a0.z - b0.z; xv[3] = a0.w - b0.w;
                xv[4] = a1.x - b1.x; xv[5] = a1.y - b1.y;
                xv[6] = a1.z - b1.z; xv[7] = a1.w - b1.w;
                if (addE) {
                    uint4 u4 = *(const uint4*)(Eb + (size_t)gr * NDIMC + ct);
                    xv[0] += __uint_as_float(u4.x << 16);
                    xv[1] += __uint_as_float(u4.x & 0xffff0000u);
                    xv[2] += __uint_as_float(u4.y << 16);
                    xv[3] += __uint_as_float(u4.y & 0xffff0000u);
                    xv[4] += __uint_as_float(u4.z << 16);
                    xv[5] += __uint_as_float(u4.z & 0xffff0000u);
                    xv[6] += __uint_as_float(u4.w << 16);
                    xv[7] += __uint_as_float(u4.w & 0xffff0000u);
                }
            }
        } else {
            if (ok) {
                float4 a0 = *(const float4*)(Xf + gr * NDIMC + ct);
                float4 a1 = *(const float4*)(Xf + gr * NDIMC + ct + 4);
                xv[0] = a0.x; xv[1] = a0.y; xv[2] = a0.z; xv[3] = a0.w;
                xv[4] = a1.x; xv[5] = a1.y; xv[6] = a1.z; xv[7] = a1.w;
                // CSR aggregate: CONTIGUOUS slot range (no indirection)
                int rs = rowstart[gr], re = rowstart[gr + 1];
                for (int k = rs; k < re; ++k) {
                    uint4 u4 = *(const uint4*)(Eb + (size_t)k * NDIMC + ct);
                    xv[0] += __uint_as_float(u4.x << 16);
                    xv[1] += __uint_as_float(u4.x & 0xffff0000u);
                    xv[2] += __uint_as_float(u4.y << 16);
                    xv[3] += __uint_as_float(u4.y & 0xffff0000u);
                    xv[4] += __uint_as_float(u4.z << 16);
                    xv[5] += __uint_as_float(u4.z & 0xffff0000u);
                    xv[6] += __uint_as_float(u4.w << 16);
                    xv[7] += __uint_as_float(u4.w & 0xffff0000u);
                }
            }
        }
#pragma unroll
        for (int t = 0; t < 8; ++t) xres[rr][t] = xv[t];
        uint4 pk;
        pk.x = mgn_pk(xv[0], xv[1]); pk.y = mgn_pk(xv[2], xv[3]);
        pk.z = mgn_pk(xv[4], xv[5]); pk.w = mgn_pk(xv[6], xv[7]);
        *(uint4*)&xl[mgn_xli(rloc, ct)] = pk;
    }

    __syncthreads();   // depth-0 Q0 visible in wqA

    mgn_sh8 a0[4], a1[4];          // A frags for the two row-tiles (full K)
    mgn_f32x4 acc0[4], acc1[4];    // one N-half of accumulators
    unsigned h2st[8][2];           // relu'd h2 nh0, packed bf16 (16 regs)
    const int rowA0 = wbase + lm;
    const int rowA1 = wbase + 16 + lm;

    for (int d = 0; d < DEPTHC; ++d) {
        const unsigned short* pw1 = PW1 + (size_t)d * 16384;
        const unsigned short* pw2 = PW2 + (size_t)d * 16384;

        // ---- A1 frags (x, full K) into regs
#pragma unroll
        for (int s = 0; s < 4; ++s) {
            a0[s] = *(const mgn_sh8*)&xl[mgn_xli(rowA0, s * 32 + q * 8)];
            a1[s] = *(const mgn_sh8*)&xl[mgn_xli(rowA1, s * 32 + q * 8)];
        }
        {   // acc init: b1 cols ct..ct+3 (N-half 0)
            float4 bb = *(const float4*)(B1 + d * NDIMC + ct);
            acc0[0] = (mgn_f32x4){bb.x, bb.x, bb.x, bb.x};
            acc0[1] = (mgn_f32x4){bb.y, bb.y, bb.y, bb.y};
            acc0[2] = (mgn_f32x4){bb.z, bb.z, bb.z, bb.z};
            acc0[3] = (mgn_f32x4){bb.w, bb.w, bb.w, bb.w};
            acc1[0] = acc0[0]; acc1[1] = acc0[1]; acc1[2] = acc0[2]; acc1[3] = acc0[3];
        }

        // ---- ph0: stage qd1->B | qd0 (nh0,h0) from A
        mgn_stage_q<BW>(pw1 + 4096, wqB, tid);
        mgn_qcompN(wqA, l, a0 + 0, a1 + 0, acc0, acc1);
        __syncthreads();
        // ---- ph1: stage qd2->A | qd1 (nh0,h1) from B; h1-nh0 stash; acc -> nh1
        mgn_stage_q<BW>(pw1 + 8192, wqA, tid);
        mgn_qcompN(wqB, l, a0 + 2, a1 + 2, acc0, acc1);
#pragma unroll
        for (int rr = 0; rr < 8; ++rr) {
            const int rloc = wbase + (rr >> 2) * 16 + q * 4 + (rr & 3);
            const int r = rr & 3;
            float v0 = fmaxf((rr < 4) ? acc0[0][r] : acc1[0][r], 0.f);
            float v1 = fmaxf((rr < 4) ? acc0[1][r] : acc1[1][r], 0.f);
            float v2 = fmaxf((rr < 4) ? acc0[2][r] : acc1[2][r], 0.f);
            float v3 = fmaxf((rr < 4) ? acc0[3][r] : acc1[3][r], 0.f);
            uint2 pk; pk.x = mgn_pk(v0, v1); pk.y = mgn_pk(v2, v3);
            *(uint2*)&xl[mgn_xli(rloc, ct)] = pk;
        }
        {   // acc init: b1 cols ct+4..ct+7 (N-half 1)
            float4 bb = *(const float4*)(B1 + d * NDIMC + ct + 4);
            acc0[0] = (mgn_f32x4){bb.x, bb.x, bb.x, bb.x};
            acc0[1] = (mgn_f32x4){bb.y, bb.y, bb.y, bb.y};
            acc0[2] = (mgn_f32x4){bb.z, bb.z, bb.z, bb.z};
            acc0[3] = (mgn_f32x4){bb.w, bb.w, bb.w, bb.w};
            acc1[0] = acc0[0]; acc1[1] = acc0[1]; acc1[2] = acc0[2]; acc1[3] = acc0[3];
        }
        __syncthreads();
        // ---- ph2: stage qd3->B | qd2 (nh1,h0) from A
        mgn_stage_q<BW>(pw1 + 12288, wqB, tid);
        mgn_qcompN(wqA, l, a0 + 0, a1 + 0, acc0, acc1);
        __syncthreads();
        // ---- ph3: stage W2 qd0->A | qd3 (nh1,h1) from B; h1-nh1 stash; A2 load; acc -> W2 nh0
        mgn_stage_q<BW>(pw2, wqA, tid);
        mgn_qcompN(wqB, l, a0 + 2, a1 + 2, acc0, acc1);
#pragma unroll
        for (int rr = 0; rr < 8; ++rr) {
            const int rloc = wbase + (rr >> 2) * 16 + q * 4 + (rr & 3);
            const int r = rr & 3;
            float v0 = fmaxf((rr < 4) ? acc0[0][r] : acc1[0][r], 0.f);
            float v1 = fmaxf((rr < 4) ? acc0[1][r] : acc1[1][r], 0.f);
            float v2 = fmaxf((rr < 4) ? acc0[2][r] : acc1[2][r], 0.f);
            float v3 = fmaxf((rr < 4) ? acc0[3][r] : acc1[3][r], 0.f);
            uint2 pk; pk.x = mgn_pk(v0, v1); pk.y = mgn_pk(v2, v3);
            *(uint2*)&xl[mgn_xli(rloc, ct + 4)] = pk;
        }
        // A2 frags (h1, full K) — xl rows complete for this wave
#pragma unroll
        for (int s = 0; s < 4; ++s) {
            a0[s] = *(const mgn_sh8*)&xl[mgn_xli(rowA0, s * 32 + q * 8)];
            a1[s] = *(const mgn_sh8*)&xl[mgn_xli(rowA1, s * 32 + q * 8)];
        }
        {   // acc init: b2 cols ct..ct+3
            float4 bb = *(const float4*)(B2 + d * NDIMC + ct);
            acc0[0] = (mgn_f32x4){bb.x, bb.x, bb.x, bb.x};
            acc0[1] = (mgn_f32x4){bb.y, bb.y, bb.y, bb.y};
            acc0[2] = (mgn_f32x4){bb.z, bb.z, bb.z, bb.z};
            acc0[3] = (mgn_f32x4){bb.w, bb.w, bb.w, bb.w};
            acc1[0] = acc0[0]; acc1[1] = acc0[1]; acc1[2] = acc0[2]; acc1[3] = acc0[3];
        }
        __syncthreads();
        // ---- ph4: stage W2 qd1->B | W2 qd0 (nh0,h0) from A
        mgn_stage_q<BW>(pw2 + 4096, wqB, tid);
        mgn_qcompN(wqA, l, a0 + 0, a1 + 0, acc0, acc1);
        __syncthreads();
        // ---- ph5: stage W2 qd2->A | W2 qd1 (nh0,h1) from B; h2-nh0 -> REGS; acc -> nh1
        mgn_stage_q<BW>(pw2 + 8192, wqA, tid);
        mgn_qcompN(wqB, l, a0 + 2, a1 + 2, acc0, acc1);
#pragma unroll
        for (int rr = 0; rr < 8; ++rr) {
            const int r = rr & 3;
            float v0 = fmaxf((rr < 4) ? acc0[0][r] : acc1[0][r], 0.f);
            float v1 = fmaxf((rr < 4) ? acc0[1][r] : acc1[1][r], 0.f);
            float v2 = fmaxf((rr < 4) ? acc0[2][r] : acc1[2][r], 0.f);
            float v3 = fmaxf((rr < 4) ? acc0[3][r] : acc1[3][r], 0.f);
            h2st[rr][0] = mgn_pk(v0, v1);
            h2st[rr][1] = mgn_pk(v2, v3);
        }
        {   // acc init: b2 cols ct+4..ct+7
            float4 bb = *(const float4*)(B2 + d * NDIMC + ct + 4);
            acc0[0] = (mgn_f32x4){bb.x, bb.x, bb.x, bb.x};
            acc0[1] = (mgn_f32x4){bb.y, bb.y, bb.y, bb.y};
            acc0[2] = (mgn_f32x4){bb.z, bb.z, bb.z, bb.z};
            acc0[3] = (mgn_f32x4){bb.w, bb.w, bb.w, bb.w};
            acc1[0] = acc0[0]; acc1[1] = acc0[1]; acc1[2] = acc0[2]; acc1[3] = acc0[3];
        }
        __syncthreads();
        // ---- ph6: stage W2 qd3->B | W2 qd2 (nh1,h0) from A
        mgn_stage_q<BW>(pw2 + 12288, wqB, tid);
        mgn_qcompN(wqA, l, a0 + 0, a1 + 0, acc0, acc1);
        __syncthreads();
        // ---- ph7: stage next-depth W1 qd0->A | W2 qd3 (nh1,h1) from B; LN epilogue
        if (d + 1 < DEPTHC)
            mgn_stage_q<BW>(PW1 + (size_t)(d + 1) * 16384, wqA, tid);
        mgn_qcompN(wqB, l, a0 + 2, a1 + 2, acc0, acc1);

        {
            float4 ga  = *(const float4*)(G  + d * NDIMC + ct);
            float4 gb  = *(const float4*)(G  + d * NDIMC + ct + 4);
            float4 bta = *(const float4*)(BT + d * NDIMC + ct);
            float4 btb = *(const float4*)(BT + d * NDIMC + ct + 4);
            float gv[8]  = {ga.x, ga.y, ga.z, ga.w, gb.x, gb.y, gb.z, gb.w};
            float btv[8] = {bta.x, bta.y, bta.z, bta.w, btb.x, btb.y, btb.z, btb.w};
#pragma unroll
            for (int rr = 0; rr < 8; ++rr) {
                const int rloc = wbase + (rr >> 2) * 16 + q * 4 + (rr & 3);
                const int r = rr & 3;
                float h2[8];
                h2[0] = __uint_as_float(h2st[rr][0] << 16);
                h2[1] = __uint_as_float(h2st[rr][0] & 0xffff0000u);
                h2[2] = __uint_as_float(h2st[rr][1] << 16);
                h2[3] = __uint_as_float(h2st[rr][1] & 0xffff0000u);
#pragma unroll
                for (int t = 0; t < 4; ++t)
                    h2[4 + t] = fmaxf((rr < 4) ? acc0[t][r] : acc1[t][r], 0.f);
                // single-pass sum & sumsq; xor1/xor2 via DPP quads, xor4 via
                // shuffle, xor8 via DPP row_ror:8 (within the 16-lane group)
                float sum = 0.f, ssq = 0.f;
#pragma unroll
                for (int t = 0; t < 8; ++t) {
                    sum += h2[t];
                    ssq = fmaf(h2[t], h2[t], ssq);
                }
                sum = mgn_dppadd<0xB1>(sum);  ssq = mgn_dppadd<0xB1>(ssq);
                sum = mgn_dppadd<0x4E>(sum);  ssq = mgn_dppadd<0x4E>(ssq);
                sum += __shfl_xor(sum, 4);    ssq += __shfl_xor(ssq, 4);
                sum = mgn_dppadd<0x128>(sum); ssq = mgn_dppadd<0x128>(ssq);
                float mean = sum * 0.0078125f;
                float var  = fmaf(-mean, mean, ssq * 0.0078125f);
                float rstd = rsqrtf(var + LNEPS);
#pragma unroll
                for (int t = 0; t < 8; ++t) {
                    float at = rstd * gv[t];
                    float ctt = fmaf(-mean, at, btv[t]);
                    xres[rr][t] += fmaf(h2[t], at, ctt);
                }
                if (d != DEPTHC - 1) {
                    uint4 pk;
                    pk.x = mgn_pk(xres[rr][0], xres[rr][1]);
                    pk.y = mgn_pk(xres[rr][2], xres[rr][3]);
                    pk.z = mgn_pk(xres[rr][4], xres[rr][5]);
                    pk.w = mgn_pk(xres[rr][6], xres[rr][7]);
                    *(uint4*)&xl[mgn_xli(rloc, ct)] = pk;
                }
            }
        }
        if (d + 1 < DEPTHC) __syncthreads();   // next-depth Q0 visible in wqA
    }

    // ---- tile store
#pragma unroll
    for (int rr = 0; rr < 8; ++rr) {
        const int rloc = wbase + (rr >> 2) * 16 + q * 4 + (rr & 3);
        long gr = rowbase + rloc;
        if (gr < nrows) {
            if (MODE == 1) {
                uint4 pk;
                pk.x = mgn_pk(xres[rr][0], xres[rr][1]);
                pk.y = mgn_pk(xres[rr][2], xres[rr][3]);
                pk.z = mgn_pk(xres[rr][4], xres[rr][5]);
                pk.w = mgn_pk(xres[rr][6], xres[rr][7]);
                *(uint4*)(Eb + (size_t)gr * NDIMC + ct) = pk;
            } else {
                float4 o0 = {xres[rr][0], xres[rr][1], xres[rr][2], xres[rr][3]};
                float4 o1 = {xres[rr][4], xres[rr][5], xres[rr][6], xres[rr][7]};
                *(float4*)(Xf + gr * NDIMC + ct)     = o0;
                *(float4*)(Xf + gr * NDIMC + ct + 4) = o1;
            }
        }
    }
}

// ---------------------------------------------------------------------------
extern "C" void kernel_launch(void* const* d_in, const int* in_sizes, int n_in,
                              void* d_out, int out_size, void* d_ws, size_t ws_size,
                              hipStream_t stream) {
    const float* v    = (const float*)d_in[0];
    const int*   ij   = (const int*)d_in[1];
    const float* encW = (const float*)d_in[2];
    const float* encB = (const float*)d_in[3];
    const float* eW1  = (const float*)d_in[4];
    const float* eB1  = (const float*)d_in[5];
    const float* eW2  = (const float*)d_in[6];
    const float* eB2  = (const float*)d_in[7];
    const float* eG   = (const float*)d_in[8];
    const float* eBT  = (const float*)d_in[9];
    const float* nW1  = (const float*)d_in[10];
    const float* nB1  = (const float*)d_in[11];
    const float* nW2  = (const float*)d_in[12];
    const float* nB2  = (const float*)d_in[13];
    const float* nG   = (const float*)d_in[14];
    const float* nBT  = (const float*)d_in[15];
    const float* decW = (const float*)d_in[16];
    const float* decB = (const float*)d_in[17];
    float* out = (float*)d_out;

    char* ws = (char*)d_ws;
    float*          h    = (float*)(ws + H_OFF);
    unsigned short* ebuf = (unsigned short*)(ws + E_OFF);
    unsigned short* pw   = (unsigned short*)(ws + PW_OFF);
    int*            flag = (int*)(ws + FLAG_OFF);
    int*            deg  = (int*)(ws + DEG_OFF);
    int*            rstt = (int*)(ws + RS_OFF);
    int*            curs = (int*)(ws + CUR_OFF);
    int*            eidx = (int*)(ws + EIDX_OFF);

    mgn_detect_kernel<<<1, 256, 0, stream>>>(ij, flag);
    mgn_pack_kernel<<<(PWMAT + 255) / 256, 256, 0, stream>>>(eW1, pw + 0 * PWMAT);
    mgn_pack_kernel<<<(PWMAT + 255) / 256, 256, 0, stream>>>(eW2, pw + 1 * PWMAT);
    mgn_pack_kernel<<<(PWMAT + 255) / 256, 256, 0, stream>>>(nW1, pw + 2 * PWMAT);
    mgn_pack_kernel<<<(PWMAT + 255) / 256, 256, 0, stream>>>(nW2, pw + 3 * PWMAT);

    // CSR build (static graph; rebuilt every call for graph-capture safety)
    hipMemsetAsync(deg, 0, (size_t)(NNODES + 1) * sizeof(int), stream);
    mgn_deg_kernel<<<(NEDGES + 255) / 256, 256, 0, stream>>>(ij, flag, deg);
    mgn_scan_kernel<<<1, 256, 0, stream>>>(deg, rstt, curs);
    mgn_fill_kernel<<<(NEDGES + 255) / 256, 256, 0, stream>>>(ij, flag, curs, eidx);

    mgn_encoder_kernel<<<(NNODES * NDIMC + 255) / 256, 256, 0, stream>>>(v, encW, encB, h);

    for (int p = 0; p < NPASSESC; ++p) {
        // edge MLP (fused gather; e in CSR-slot order; 128 rows/block)
        mgn_mlp6_mfma_kernel<1, 4><<<NEDGES / 128, 256, 0, stream>>>(
            nullptr, ebuf, h, ij, flag, nullptr, eidx, p > 0 ? 1 : 0, NEDGES,
            pw + 0 * PWMAT, pw + 1 * PWMAT, eB1, eB2, eG, eBT);
        // node MLP with fused CSR aggregation (contiguous Eb reads; 128 rows/block)
        mgn_mlp6_mfma_kernel<0, 4><<<(NNODES + 127) / 128, 256, 0, stream>>>(
            h, ebuf, nullptr, nullptr, nullptr, rstt, nullptr, 0, NNODES,
            pw + 2 * PWMAT, pw + 3 * PWMAT, nB1, nB2, nG, nBT);
    }

    mgn_decoder_kernel<<<(NNODES * NODEIN + 255) / 256, 256, 0, stream>>>(h, decW, decB, out);
}

// Round 6
// 3002.533 us; speedup vs baseline: 1.6880x; 1.6880x over previous
//
#include <hip/hip_runtime.h>
#include <hip/hip_bf16.h>
#include <cstdint>
#include <cstddef>

#define NDIMC   128
#define DEPTHC  6
#define NPASSESC 4
#define NNODES  50000
#define NEDGES  800000
#define NODEIN  5
#define LNEPS   1e-5f

// ---------------------------------------------------------------------------
// ws layout (bytes) — ~224 MiB, below proven-safe 256,000,004
#define H_OFF    0ull                     // h:  50000*128*4  = 25.6 MB fp32
#define E_OFF    25600000ull              // e:  800000*128*2 = 204.8 MB bf16 (CSR-slot order)
#define PW_OFF   230400000ull             // packed weights: 4 * 196,608 B bf16
#define FLAG_OFF 231186432ull
#define DEG_OFF  231186436ull             // 50001 int
#define RS_OFF   231386440ull             // rowstart: 50001 int
#define CUR_OFF  231586444ull             // cursor:   50000 int
#define EIDX_OFF 231786444ull             // eidx:     800000 int -> ends 234,986,444
#define PWMAT    98304                    // shorts per packed matrix (6*4*4096)

typedef __attribute__((ext_vector_type(8))) short mgn_sh8;
typedef __attribute__((ext_vector_type(4))) float mgn_f32x4;

// ---------------------------------------------------------------------------
__device__ __forceinline__ unsigned mgn_bf16bits(float f) {
    unsigned x = __float_as_uint(f);
    return (x + 0x7fffu + ((x >> 16) & 1u)) >> 16;   // RNE
}
__device__ __forceinline__ unsigned mgn_pk(float a, float b) {
    __hip_bfloat162 t = __float22bfloat162_rn(make_float2(a, b));
    union { __hip_bfloat162 h; unsigned u; } c; c.h = t; return c.u;
}

// DPP-based partial butterfly (VALU, off the LDS pipe). Correctness proven in
// r21 (passed). 0xB1 = quad_perm lane^1; 0x4E = quad_perm lane^2;
// 0x128 = row_ror:8 == lane^8 within each 16-lane row.
template <int CTRL>
__device__ __forceinline__ float mgn_dppadd(float x) {
    int y = __builtin_amdgcn_update_dpp(0, __float_as_int(x), CTRL, 0xF, 0xF, true);
    return x + __int_as_float(y);
}

// Bijective XCD-chunked block swizzle (m204): consecutive CSR-ordered blocks
// land on the same XCD -> contiguous dst-node ranges per XCD L2 (h gather
// locality). Handles nwg % 8 != 0 bijectively.
__device__ __forceinline__ int mgn_swz(int orig, int nwg) {
    int qq = nwg >> 3, rr = nwg & 7;
    int xcd = orig & 7, idx = orig >> 3;
    int base = (xcd < rr) ? xcd * (qq + 1) : rr * (qq + 1) + (xcd - rr) * qq;
    return base + idx;
}

// async 16B global->LDS DMA (no VGPR round-trip; tracked by vmcnt)
__device__ __forceinline__ void mgn_cp16(const unsigned short* g, unsigned short* l) {
    __builtin_amdgcn_global_load_lds(
        (const __attribute__((address_space(1))) void*)g,
        (__attribute__((address_space(3))) void*)l, 16, 0, 0);
}
// Stage one 8 KB weight QUARTER (4096 shorts = 8 chunks of 512) with BW waves.
template <int BW>
__device__ __forceinline__ void mgn_stage_q(const unsigned short* __restrict__ src,
                                            unsigned short* wbuf, int tid) {
    const int w = tid >> 6, l = tid & 63;
#pragma unroll
    for (int i = 0; i < 8 / BW; ++i) {
        const int off = (w * (8 / BW) + i) * 512 + l * 8;   // shorts
        mgn_cp16(src + off, wbuf + off);
    }
}

// One weight-quarter of MFMAs: 4 t'-groups x 2 sp, both row-tiles, ONE N-half.
// a0p/a1p point at the K-half's A-frag pair. acc = 4 per row-tile (N-half).
// s_setprio(1) keeps the matrix pipe fed while other waves stage (T5).
__device__ __forceinline__ void mgn_qcompN(const unsigned short* __restrict__ buf, int l,
                                           const mgn_sh8* a0p, const mgn_sh8* a1p,
                                           mgn_f32x4* acc0, mgn_f32x4* acc1) {
    __builtin_amdgcn_s_setprio(1);
#pragma unroll
    for (int t = 0; t < 4; ++t)
#pragma unroll
        for (int sp = 0; sp < 2; ++sp) {
            mgn_sh8 b = *(const mgn_sh8*)&buf[(t * 2 + sp) * 512 + l * 8];
            acc0[t] = __builtin_amdgcn_mfma_f32_16x16x32_bf16(a0p[sp], b, acc0[t], 0, 0, 0);
            acc1[t] = __builtin_amdgcn_mfma_f32_16x16x32_bf16(a1p[sp], b, acc1[t], 0, 0, 0);
        }
    __builtin_amdgcn_s_setprio(0);
}

// ---------------------------------------------------------------------------
// flag = 1 -> ij is int32, flag = 0 -> ij is int64
__global__ void mgn_detect_kernel(const int* __restrict__ ij, int* __restrict__ flag) {
    __shared__ int any;
    if (threadIdx.x == 0) any = 0;
    __syncthreads();
    if (ij[2 * threadIdx.x + 1] != 0) atomicOr(&any, 1);
    __syncthreads();
    if (threadIdx.x == 0) *flag = any;
}

__device__ __forceinline__ long mgn_load_idx(const int* __restrict__ ij, long pos, int is32) {
    if (is32) return (long)ij[pos];
    const long long* ij8 = (const long long*)ij;
    return (long)ij8[pos];
}

// ---------------------------------------------------------------------------
// Pack fp32 row-major W[d][k][n] into QUARTER-streamed MFMA B-frag order.
// Quarter qd = nh*2 + sh  (nh = N-half, sh = K-half) is a contiguous 8 KB
// block, in the exact order the N-split schedule consumes them:
//   qd0=(nh0,h0) qd1=(nh0,h1) qd2=(nh1,h0) qd3=(nh1,h1)
// i = ((((d*4+qd)*4+t')*2+sp)*64+lane)*8+j holds
//   W[d][(sh*2+sp)*32 + (lane>>4)*8 + j][(lane&15)*8 + nh*4 + t']
__global__ void mgn_pack_kernel(const float* __restrict__ W, unsigned short* __restrict__ pw) {
    int i = blockIdx.x * blockDim.x + threadIdx.x;
    if (i >= PWMAT) return;
    int j    = i & 7;
    int lane = (i >> 3) & 63;
    int sp   = (i >> 9) & 1;
    int tp   = (i >> 10) & 3;
    int qd   = (i >> 12) & 3;
    int d    = i >> 14;
    int sh = qd & 1, nh = qd >> 1;
    int k = (sh * 2 + sp) * 32 + (lane >> 4) * 8 + j;
    int n = (lane & 15) * 8 + nh * 4 + tp;
    pw[i] = (unsigned short)mgn_bf16bits(W[(d * NDIMC + k) * NDIMC + n]);
}

// ---------------------------------------------------------------------------
// CSR build: histogram -> scan -> fill
__global__ void mgn_deg_kernel(const int* __restrict__ ij, const int* __restrict__ flag,
                               int* __restrict__ deg) {
    int e = blockIdx.x * blockDim.x + threadIdx.x;
    if (e >= NEDGES) return;
    int dst = (int)mgn_load_idx(ij, (long)NEDGES + e, *flag);
    atomicAdd(&deg[dst], 1);
}

__global__ void mgn_scan_kernel(const int* __restrict__ deg,
                                int* __restrict__ rowstart, int* __restrict__ cursor) {
    __shared__ int partial[256];
    const int tid = threadIdx.x;
    const int CH = (NNODES + 255) / 256;   // 196
    const int base = tid * CH;
    int s = 0;
    for (int i = 0; i < CH; ++i) {
        int idx = base + i;
        if (idx < NNODES) s += deg[idx];
    }
    partial[tid] = s;
    __syncthreads();
    for (int off = 1; off < 256; off <<= 1) {
        int add = (tid >= off) ? partial[tid - off] : 0;
        __syncthreads();
        partial[tid] += add;
        __syncthreads();
    }
    int run = (tid == 0) ? 0 : partial[tid - 1];
    for (int i = 0; i < CH; ++i) {
        int idx = base + i;
        if (idx < NNODES) {
            rowstart[idx] = run;
            cursor[idx]   = run;
            run += deg[idx];
        }
    }
    if (tid == 255) rowstart[NNODES] = run;
}

__global__ void mgn_fill_kernel(const int* __restrict__ ij, const int* __restrict__ flag,
                                int* __restrict__ cursor, int* __restrict__ eidx) {
    int e = blockIdx.x * blockDim.x + threadIdx.x;
    if (e >= NEDGES) return;
    int dst = (int)mgn_load_idx(ij, (long)NEDGES + e, *flag);
    int pos = atomicAdd(&cursor[dst], 1);
    eidx[pos] = e;
}

// ---------------------------------------------------------------------------
__global__ void mgn_encoder_kernel(const float* __restrict__ v,
                                   const float* __restrict__ encW,
                                   const float* __restrict__ encB,
                                   float* __restrict__ h) {
    int idx = blockIdx.x * blockDim.x + threadIdx.x;
    if (idx >= NNODES * NDIMC) return;
    int n = idx >> 7, d = idx & 127;
    float acc = encB[d];
#pragma unroll
    for (int k = 0; k < NODEIN; ++k)
        acc = fmaf(v[n * NODEIN + k], encW[k * NDIMC + d], acc);
    h[idx] = acc;
}

__global__ void mgn_decoder_kernel(const float* __restrict__ h,
                                   const float* __restrict__ decW,
                                   const float* __restrict__ decB,
                                   float* __restrict__ out) {
    int idx = blockIdx.x * blockDim.x + threadIdx.x;
    if (idx >= NNODES * NODEIN) return;
    int n = idx / NODEIN, j = idx % NODEIN;
    float acc = decB[j];
#pragma unroll 8
    for (int k = 0; k < NDIMC; ++k)
        acc = fmaf(h[n * NDIMC + k], decW[k * NODEIN + j], acc);
    out[idx] = acc;
}

// ---------------------------------------------------------------------------
// Fused 6-deep residual MLP, bf16 MFMA core, fp32 residual/LN.
// r22: RECOVERY. r21 post-mortem: h2st regs (+16) + per-access swizzle temps
// re-triggered scratch spilling (FETCH 472MB->1.12GB, WRITE 300->773MB) —
// at occupancy-3 the register budget is THE binding constraint; r20 sits at
// the edge. This round = exact r20 structure (stride-136 xl, uint2 stashes,
// h2-nh0 stash in xl) + only ZERO-REGISTER-PRESSURE changes:
//  1. DPP LN reduce (xor1/xor2 quad_perm, xor8 row_ror:8; r21-proven) — off
//     the LDS pipe
//  2. s_setprio(1) around MFMA clusters (T5)
//  3. bijective XCD-chunked block swizzle (CSR-ordered blocks share dst-node
//     h rows -> per-XCD L2 gather locality)
// Geometry: M=32/wave, N-split GEMMs, 8 KB quarter ping-pong, 8 phases/depth,
// 3 blocks/CU.
template <int MODE, int BW>
__global__ __launch_bounds__(BW * 64, 3) void mgn_mlp6_mfma_kernel(
    float* __restrict__ Xf,               // node: h
    unsigned short* __restrict__ Eb,      // e buffer (CSR-slot order)
    const float* __restrict__ H,          // edge: h for gather
    const int* __restrict__ ij,
    const int* __restrict__ flag,
    const int* __restrict__ rowstart,     // node CSR
    const int* __restrict__ eidx,         // edge: slot -> original edge id
    int addE, int nrows,
    const unsigned short* __restrict__ PW1,
    const unsigned short* __restrict__ PW2,
    const float* __restrict__ B1, const float* __restrict__ B2,
    const float* __restrict__ G,  const float* __restrict__ BT)
{
    __shared__ unsigned short xl[BW * 32 * 136];   // x/h1 tile, row stride 136 (34816 B)
    __shared__ unsigned short wqA[4096];           // weight quarter ping (8 KB)
    __shared__ unsigned short wqB[4096];           // weight quarter pong (8 KB)
    const int tid = threadIdx.x;
    const int w   = tid >> 6;
    const int l   = tid & 63;
    const int q   = l >> 4;
    const int lm  = l & 15;
    const int ct  = lm * 8;                        // first of lane's 8 cols
    const int wbase = w * 32;                      // wave's first local row
    const int bid = mgn_swz((int)blockIdx.x, (int)gridDim.x);
    const long rowbase = (long)bid * (32 * BW);

    const int is32 = (MODE == 1) ? *flag : 0;

    // pre-stage depth-0 W1 quarter 0 -> wqA; drains at first barrier
    mgn_stage_q<BW>(PW1, wqA, tid);

    // ---- tile load: xres fp32 regs (C layout) + LDS bf16 (A source)
    // lane owns 8 rows: row-tile u = rr>>2, r = rr&3
    float xres[8][8];
#pragma unroll
    for (int rr = 0; rr < 8; ++rr) {
        const int rloc = wbase + (rr >> 2) * 16 + q * 4 + (rr & 3);
        long gr = rowbase + rloc;
        bool ok = gr < nrows;
        float xv[8];
#pragma unroll
        for (int t = 0; t < 8; ++t) xv[t] = 0.f;
        if (MODE == 1) {
            if (ok) {
                long er = (long)eidx[gr];     // original edge id for this slot
                long i0 = mgn_load_idx(ij, er, is32);
                long i1 = mgn_load_idx(ij, (long)NEDGES + er, is32);
                const float* p0 = H + i0 * NDIMC + ct;
                const float* p1 = H + i1 * NDIMC + ct;
                float4 a0 = *(const float4*)p0, a1 = *(const float4*)(p0 + 4);
                float4 b0 = *(const float4*)p1, b1 = *(const float4*)(p1 + 4);
                xv[0] = a0.x - b0.x; xv[1] = a0.y - b0.y;
                xv[2] = a0.z - b0.z; xv[3] = a0.w - b0.w;
                xv[4] = a1.x - b1.x; xv[5] = a1.y - b1.y;
                xv[6] = a1.z - b1.z; xv[7] = a1.w - b1.w;
                if (addE) {
                    uint4 u4 = *(const uint4*)(Eb + (size_t)gr * NDIMC + ct);
                    xv[0] += __uint_as_float(u4.x << 16);
                    xv[1] += __uint_as_float(u4.x & 0xffff0000u);
                    xv[2] += __uint_as_float(u4.y << 16);
                    xv[3] += __uint_as_float(u4.y & 0xffff0000u);
                    xv[4] += __uint_as_float(u4.z << 16);
                    xv[5] += __uint_as_float(u4.z & 0xffff0000u);
                    xv[6] += __uint_as_float(u4.w << 16);
                    xv[7] += __uint_as_float(u4.w & 0xffff0000u);
                }
            }
        } else {
            if (ok) {
                float4 a0 = *(const float4*)(Xf + gr * NDIMC + ct);
                float4 a1 = *(const float4*)(Xf + gr * NDIMC + ct + 4);
                xv[0] = a0.x; xv[1] = a0.y; xv[2] = a0.z; xv[3] = a0.w;
                xv[4] = a1.x; xv[5] = a1.y; xv[6] = a1.z; xv[7] = a1.w;
                // CSR aggregate: CONTIGUOUS slot range (no indirection)
                int rs = rowstart[gr], re = rowstart[gr + 1];
                for (int k = rs; k < re; ++k) {
                    uint4 u4 = *(const uint4*)(Eb + (size_t)k * NDIMC + ct);
                    xv[0] += __uint_as_float(u4.x << 16);
                    xv[1] += __uint_as_float(u4.x & 0xffff0000u);
                    xv[2] += __uint_as_float(u4.y << 16);
                    xv[3] += __uint_as_float(u4.y & 0xffff0000u);
                    xv[4] += __uint_as_float(u4.z << 16);
                    xv[5] += __uint_as_float(u4.z & 0xffff0000u);
                    xv[6] += __uint_as_float(u4.w << 16);
                    xv[7] += __uint_as_float(u4.w & 0xffff0000u);
                }
            }
        }
#pragma unroll
        for (int t = 0; t < 8; ++t) xres[rr][t] = xv[t];
        uint4 pk;
        pk.x = mgn_pk(xv[0], xv[1]); pk.y = mgn_pk(xv[2], xv[3]);
        pk.z = mgn_pk(xv[4], xv[5]); pk.w = mgn_pk(xv[6], xv[7]);
        *(uint4*)&xl[rloc * 136 + ct] = pk;
    }

    __syncthreads();   // depth-0 Q0 visible in wqA

    mgn_sh8 a0[4], a1[4];          // A frags for the two row-tiles (full K)
    mgn_f32x4 acc0[4], acc1[4];    // one N-half of accumulators
    const int arow0 = (wbase + lm) * 136;
    const int arow1 = (wbase + 16 + lm) * 136;

    for (int d = 0; d < DEPTHC; ++d) {
        const unsigned short* pw1 = PW1 + (size_t)d * 16384;
        const unsigned short* pw2 = PW2 + (size_t)d * 16384;

        // ---- A1 frags (x, full K) into regs
#pragma unroll
        for (int s = 0; s < 4; ++s) {
            a0[s] = *(const mgn_sh8*)&xl[arow0 + s * 32 + q * 8];
            a1[s] = *(const mgn_sh8*)&xl[arow1 + s * 32 + q * 8];
        }
        {   // acc init: b1 cols ct..ct+3 (N-half 0)
            float4 bb = *(const float4*)(B1 + d * NDIMC + ct);
            acc0[0] = (mgn_f32x4){bb.x, bb.x, bb.x, bb.x};
            acc0[1] = (mgn_f32x4){bb.y, bb.y, bb.y, bb.y};
            acc0[2] = (mgn_f32x4){bb.z, bb.z, bb.z, bb.z};
            acc0[3] = (mgn_f32x4){bb.w, bb.w, bb.w, bb.w};
            acc1[0] = acc0[0]; acc1[1] = acc0[1]; acc1[2] = acc0[2]; acc1[3] = acc0[3];
        }

        // ---- ph0: stage qd1->B | qd0 (nh0,h0) from A
        mgn_stage_q<BW>(pw1 + 4096, wqB, tid);
        mgn_qcompN(wqA, l, a0 + 0, a1 + 0, acc0, acc1);
        __syncthreads();
        // ---- ph1: stage qd2->A | qd1 (nh0,h1) from B; h1-nh0 stash; acc -> nh1
        mgn_stage_q<BW>(pw1 + 8192, wqA, tid);
        mgn_qcompN(wqB, l, a0 + 2, a1 + 2, acc0, acc1);
#pragma unroll
        for (int rr = 0; rr < 8; ++rr) {
            const int rloc = wbase + (rr >> 2) * 16 + q * 4 + (rr & 3);
            const int r = rr & 3;
            float v0 = fmaxf((rr < 4) ? acc0[0][r] : acc1[0][r], 0.f);
            float v1 = fmaxf((rr < 4) ? acc0[1][r] : acc1[1][r], 0.f);
            float v2 = fmaxf((rr < 4) ? acc0[2][r] : acc1[2][r], 0.f);
            float v3 = fmaxf((rr < 4) ? acc0[3][r] : acc1[3][r], 0.f);
            uint2 pk; pk.x = mgn_pk(v0, v1); pk.y = mgn_pk(v2, v3);
            *(uint2*)&xl[rloc * 136 + ct] = pk;
        }
        {   // acc init: b1 cols ct+4..ct+7 (N-half 1)
            float4 bb = *(const float4*)(B1 + d * NDIMC + ct + 4);
            acc0[0] = (mgn_f32x4){bb.x, bb.x, bb.x, bb.x};
            acc0[1] = (mgn_f32x4){bb.y, bb.y, bb.y, bb.y};
            acc0[2] = (mgn_f32x4){bb.z, bb.z, bb.z, bb.z};
            acc0[3] = (mgn_f32x4){bb.w, bb.w, bb.w, bb.w};
            acc1[0] = acc0[0]; acc1[1] = acc0[1]; acc1[2] = acc0[2]; acc1[3] = acc0[3];
        }
        __syncthreads();
        // ---- ph2: stage qd3->B | qd2 (nh1,h0) from A
        mgn_stage_q<BW>(pw1 + 12288, wqB, tid);
        mgn_qcompN(wqA, l, a0 + 0, a1 + 0, acc0, acc1);
        __syncthreads();
        // ---- ph3: stage W2 qd0->A | qd3 (nh1,h1) from B; h1-nh1 stash; A2 load; acc -> W2 nh0
        mgn_stage_q<BW>(pw2, wqA, tid);
        mgn_qcompN(wqB, l, a0 + 2, a1 + 2, acc0, acc1);
#pragma unroll
        for (int rr = 0; rr < 8; ++rr) {
            const int rloc = wbase + (rr >> 2) * 16 + q * 4 + (rr & 3);
            const int r = rr & 3;
            float v0 = fmaxf((rr < 4) ? acc0[0][r] : acc1[0][r], 0.f);
            float v1 = fmaxf((rr < 4) ? acc0[1][r] : acc1[1][r], 0.f);
            float v2 = fmaxf((rr < 4) ? acc0[2][r] : acc1[2][r], 0.f);
            float v3 = fmaxf((rr < 4) ? acc0[3][r] : acc1[3][r], 0.f);
            uint2 pk; pk.x = mgn_pk(v0, v1); pk.y = mgn_pk(v2, v3);
            *(uint2*)&xl[rloc * 136 + ct + 4] = pk;
        }
        // A2 frags (h1, full K) — xl rows complete for this wave
#pragma unroll
        for (int s = 0; s < 4; ++s) {
            a0[s] = *(const mgn_sh8*)&xl[arow0 + s * 32 + q * 8];
            a1[s] = *(const mgn_sh8*)&xl[arow1 + s * 32 + q * 8];
        }
        {   // acc init: b2 cols ct..ct+3
            float4 bb = *(const float4*)(B2 + d * NDIMC + ct);
            acc0[0] = (mgn_f32x4){bb.x, bb.x, bb.x, bb.x};
            acc0[1] = (mgn_f32x4){bb.y, bb.y, bb.y, bb.y};
            acc0[2] = (mgn_f32x4){bb.z, bb.z, bb.z, bb.z};
            acc0[3] = (mgn_f32x4){bb.w, bb.w, bb.w, bb.w};
            acc1[0] = acc0[0]; acc1[1] = acc0[1]; acc1[2] = acc0[2]; acc1[3] = acc0[3];
        }
        __syncthreads();
        // ---- ph4: stage W2 qd1->B | W2 qd0 (nh0,h0) from A
        mgn_stage_q<BW>(pw2 + 4096, wqB, tid);
        mgn_qcompN(wqA, l, a0 + 0, a1 + 0, acc0, acc1);
        __syncthreads();
        // ---- ph5: stage W2 qd2->A | W2 qd1 (nh0,h1) from B; h2-nh0 stash; acc -> nh1
        mgn_stage_q<BW>(pw2 + 8192, wqA, tid);
        mgn_qcompN(wqB, l, a0 + 2, a1 + 2, acc0, acc1);
#pragma unroll
        for (int rr = 0; rr < 8; ++rr) {
            const int rloc = wbase + (rr >> 2) * 16 + q * 4 + (rr & 3);
            const int r = rr & 3;
            float v0 = fmaxf((rr < 4) ? acc0[0][r] : acc1[0][r], 0.f);
            float v1 = fmaxf((rr < 4) ? acc0[1][r] : acc1[1][r], 0.f);
            float v2 = fmaxf((rr < 4) ? acc0[2][r] : acc1[2][r], 0.f);
            float v3 = fmaxf((rr < 4) ? acc0[3][r] : acc1[3][r], 0.f);
            uint2 pk; pk.x = mgn_pk(v0, v1); pk.y = mgn_pk(v2, v3);
            *(uint2*)&xl[rloc * 136 + ct] = pk;   // h1 fully consumed into a-regs
        }
        {   // acc init: b2 cols ct+4..ct+7
            float4 bb = *(const float4*)(B2 + d * NDIMC + ct + 4);
            acc0[0] = (mgn_f32x4){bb.x, bb.x, bb.x, bb.x};
            acc0[1] = (mgn_f32x4){bb.y, bb.y, bb.y, bb.y};
            acc0[2] = (mgn_f32x4){bb.z, bb.z, bb.z, bb.z};
            acc0[3] = (mgn_f32x4){bb.w, bb.w, bb.w, bb.w};
            acc1[0] = acc0[0]; acc1[1] = acc0[1]; acc1[2] = acc0[2]; acc1[3] = acc0[3];
        }
        __syncthreads();
        // ---- ph6: stage W2 qd3->B | W2 qd2 (nh1,h0) from A
        mgn_stage_q<BW>(pw2 + 12288, wqB, tid);
        mgn_qcompN(wqA, l, a0 + 0, a1 + 0, acc0, acc1);
        __syncthreads();
        // ---- ph7: stage next-depth W1 qd0->A | W2 qd3 (nh1,h1) from B; LN epilogue
        if (d + 1 < DEPTHC)
            mgn_stage_q<BW>(PW1 + (size_t)(d + 1) * 16384, wqA, tid);
        mgn_qcompN(wqB, l, a0 + 2, a1 + 2, acc0, acc1);

        {
            float4 ga  = *(const float4*)(G  + d * NDIMC + ct);
            float4 gb  = *(const float4*)(G  + d * NDIMC + ct + 4);
            float4 bta = *(const float4*)(BT + d * NDIMC + ct);
            float4 btb = *(const float4*)(BT + d * NDIMC + ct + 4);
            float gv[8]  = {ga.x, ga.y, ga.z, ga.w, gb.x, gb.y, gb.z, gb.w};
            float btv[8] = {bta.x, bta.y, bta.z, bta.w, btb.x, btb.y, btb.z, btb.w};
#pragma unroll
            for (int rr = 0; rr < 8; ++rr) {
                const int rloc = wbase + (rr >> 2) * 16 + q * 4 + (rr & 3);
                const int r = rr & 3;
                float h2[8];
                uint2 st = *(const uint2*)&xl[rloc * 136 + ct];   // relu'd nh0 (bf16)
                h2[0] = __uint_as_float(st.x << 16);
                h2[1] = __uint_as_float(st.x & 0xffff0000u);
                h2[2] = __uint_as_float(st.y << 16);
                h2[3] = __uint_as_float(st.y & 0xffff0000u);
#pragma unroll
                for (int t = 0; t < 4; ++t)
                    h2[4 + t] = fmaxf((rr < 4) ? acc0[t][r] : acc1[t][r], 0.f);
                // single-pass sum & sumsq; xor1/xor2 via DPP quads, xor4 via
                // shuffle, xor8 via DPP row_ror:8 (within the 16-lane group)
                float sum = 0.f, ssq = 0.f;
#pragma unroll
                for (int t = 0; t < 8; ++t) {
                    sum += h2[t];
                    ssq = fmaf(h2[t], h2[t], ssq);
                }
                sum = mgn_dppadd<0xB1>(sum);  ssq = mgn_dppadd<0xB1>(ssq);
                sum = mgn_dppadd<0x4E>(sum);  ssq = mgn_dppadd<0x4E>(ssq);
                sum += __shfl_xor(sum, 4);    ssq += __shfl_xor(ssq, 4);
                sum = mgn_dppadd<0x128>(sum); ssq = mgn_dppadd<0x128>(ssq);
                float mean = sum * 0.0078125f;
                float var  = fmaf(-mean, mean, ssq * 0.0078125f);
                float rstd = rsqrtf(var + LNEPS);
#pragma unroll
                for (int t = 0; t < 8; ++t) {
                    float at = rstd * gv[t];
                    float ctt = fmaf(-mean, at, btv[t]);
                    xres[rr][t] += fmaf(h2[t], at, ctt);
                }
                if (d != DEPTHC - 1) {
                    uint4 pk;
                    pk.x = mgn_pk(xres[rr][0], xres[rr][1]);
                    pk.y = mgn_pk(xres[rr][2], xres[rr][3]);
                    pk.z = mgn_pk(xres[rr][4], xres[rr][5]);
                    pk.w = mgn_pk(xres[rr][6], xres[rr][7]);
                    *(uint4*)&xl[rloc * 136 + ct] = pk;
                }
            }
        }
        if (d + 1 < DEPTHC) __syncthreads();   // next-depth Q0 visible in wqA
    }

    // ---- tile store
#pragma unroll
    for (int rr = 0; rr < 8; ++rr) {
        const int rloc = wbase + (rr >> 2) * 16 + q * 4 + (rr & 3);
        long gr = rowbase + rloc;
        if (gr < nrows) {
            if (MODE == 1) {
                uint4 pk;
                pk.x = mgn_pk(xres[rr][0], xres[rr][1]);
                pk.y = mgn_pk(xres[rr][2], xres[rr][3]);
                pk.z = mgn_pk(xres[rr][4], xres[rr][5]);
                pk.w = mgn_pk(xres[rr][6], xres[rr][7]);
                *(uint4*)(Eb + (size_t)gr * NDIMC + ct) = pk;
            } else {
                float4 o0 = {xres[rr][0], xres[rr][1], xres[rr][2], xres[rr][3]};
                float4 o1 = {xres[rr][4], xres[rr][5], xres[rr][6], xres[rr][7]};
                *(float4*)(Xf + gr * NDIMC + ct)     = o0;
                *(float4*)(Xf + gr * NDIMC + ct + 4) = o1;
            }
        }
    }
}

// ---------------------------------------------------------------------------
extern "C" void kernel_launch(void* const* d_in, const int* in_sizes, int n_in,
                              void* d_out, int out_size, void* d_ws, size_t ws_size,
                              hipStream_t stream) {
    const float* v    = (const float*)d_in[0];
    const int*   ij   = (const int*)d_in[1];
    const float* encW = (const float*)d_in[2];
    const float* encB = (const float*)d_in[3];
    const float* eW1  = (const float*)d_in[4];
    const float* eB1  = (const float*)d_in[5];
    const float* eW2  = (const float*)d_in[6];
    const float* eB2  = (const float*)d_in[7];
    const float* eG   = (const float*)d_in[8];
    const float* eBT  = (const float*)d_in[9];
    const float* nW1  = (const float*)d_in[10];
    const float* nB1  = (const float*)d_in[11];
    const float* nW2  = (const float*)d_in[12];
    const float* nB2  = (const float*)d_in[13];
    const float* nG   = (const float*)d_in[14];
    const float* nBT  = (const float*)d_in[15];
    const float* decW = (const float*)d_in[16];
    const float* decB = (const float*)d_in[17];
    float* out = (float*)d_out;

    char* ws = (char*)d_ws;
    float*          h    = (float*)(ws + H_OFF);
    unsigned short* ebuf = (unsigned short*)(ws + E_OFF);
    unsigned short* pw   = (unsigned short*)(ws + PW_OFF);
    int*            flag = (int*)(ws + FLAG_OFF);
    int*            deg  = (int*)(ws + DEG_OFF);
    int*            rstt = (int*)(ws + RS_OFF);
    int*            curs = (int*)(ws + CUR_OFF);
    int*            eidx = (int*)(ws + EIDX_OFF);

    mgn_detect_kernel<<<1, 256, 0, stream>>>(ij, flag);
    mgn_pack_kernel<<<(PWMAT + 255) / 256, 256, 0, stream>>>(eW1, pw + 0 * PWMAT);
    mgn_pack_kernel<<<(PWMAT + 255) / 256, 256, 0, stream>>>(eW2, pw + 1 * PWMAT);
    mgn_pack_kernel<<<(PWMAT + 255) / 256, 256, 0, stream>>>(nW1, pw + 2 * PWMAT);
    mgn_pack_kernel<<<(PWMAT + 255) / 256, 256, 0, stream>>>(nW2, pw + 3 * PWMAT);

    // CSR build (static graph; rebuilt every call for graph-capture safety)
    hipMemsetAsync(deg, 0, (size_t)(NNODES + 1) * sizeof(int), stream);
    mgn_deg_kernel<<<(NEDGES + 255) / 256, 256, 0, stream>>>(ij, flag, deg);
    mgn_scan_kernel<<<1, 256, 0, stream>>>(deg, rstt, curs);
    mgn_fill_kernel<<<(NEDGES + 255) / 256, 256, 0, stream>>>(ij, flag, curs, eidx);

    mgn_encoder_kernel<<<(NNODES * NDIMC + 255) / 256, 256, 0, stream>>>(v, encW, encB, h);

    for (int p = 0; p < NPASSESC; ++p) {
        // edge MLP (fused gather; e in CSR-slot order; 128 rows/block)
        mgn_mlp6_mfma_kernel<1, 4><<<NEDGES / 128, 256, 0, stream>>>(
            nullptr, ebuf, h, ij, flag, nullptr, eidx, p > 0 ? 1 : 0, NEDGES,
            pw + 0 * PWMAT, pw + 1 * PWMAT, eB1, eB2, eG, eBT);
        // node MLP with fused CSR aggregation (contiguous Eb reads; 128 rows/block)
        mgn_mlp6_mfma_kernel<0, 4><<<(NNODES + 127) / 128, 256, 0, stream>>>(
            h, ebuf, nullptr, nullptr, nullptr, rstt, nullptr, 0, NNODES,
            pw + 2 * PWMAT, pw + 3 * PWMAT, nB1, nB2, nG, nBT);
    }

    mgn_decoder_kernel<<<(NNODES * NODEIN + 255) / 256, 256, 0, stream>>>(h, decW, decB, out);
}

// Round 7
// 2822.061 us; speedup vs baseline: 1.7959x; 1.0640x over previous
//
#include <hip/hip_runtime.h>
#include <hip/hip_bf16.h>
#include <cstdint>
#include <cstddef>

#define NDIMC   128
#define DEPTHC  6
#define NPASSESC 4
#define NNODES  50000
#define NEDGES  800000
#define NODEIN  5
#define LNEPS   1e-5f

// ---------------------------------------------------------------------------
// ws layout (bytes) — ~224 MiB, below proven-safe 256,000,004
#define H_OFF    0ull                     // h:  50000*128*4  = 25.6 MB fp32
#define E_OFF    25600000ull              // e:  800000*128*2 = 204.8 MB bf16 (CSR-slot order)
#define PW_OFF   230400000ull             // packed weights: 4 * 196,608 B bf16
#define FLAG_OFF 231186432ull
#define DEG_OFF  231186436ull             // 50001 int
#define RS_OFF   231386440ull             // rowstart: 50001 int
#define CUR_OFF  231586444ull             // cursor:   50000 int
#define EIDX_OFF 231786444ull             // eidx:     800000 int -> ends 234,986,444
#define PWMAT    98304                    // shorts per packed matrix (6*2*8192)

typedef __attribute__((ext_vector_type(8))) short mgn_sh8;
typedef __attribute__((ext_vector_type(4))) float mgn_f32x4;

// ---------------------------------------------------------------------------
__device__ __forceinline__ unsigned mgn_bf16bits(float f) {
    unsigned x = __float_as_uint(f);
    return (x + 0x7fffu + ((x >> 16) & 1u)) >> 16;   // RNE
}
__device__ __forceinline__ unsigned mgn_pk(float a, float b) {
    __hip_bfloat162 t = __float22bfloat162_rn(make_float2(a, b));
    union { __hip_bfloat162 h; unsigned u; } c; c.h = t; return c.u;
}

// DPP-based partial butterfly (VALU, off the LDS pipe). r21/r22-proven.
// 0xB1 = quad_perm lane^1; 0x4E = quad_perm lane^2; 0x128 = row_ror:8 = lane^8
// within each 16-lane row.
template <int CTRL>
__device__ __forceinline__ float mgn_dppadd(float x) {
    int y = __builtin_amdgcn_update_dpp(0, __float_as_int(x), CTRL, 0xF, 0xF, true);
    return x + __int_as_float(y);
}

// Bijective XCD-chunked block swizzle (m204): consecutive CSR-ordered blocks
// land on the same XCD -> contiguous dst-node ranges per XCD L2.
__device__ __forceinline__ int mgn_swz(int orig, int nwg) {
    int qq = nwg >> 3, rr = nwg & 7;
    int xcd = orig & 7, idx = orig >> 3;
    int base = (xcd < rr) ? xcd * (qq + 1) : rr * (qq + 1) + (xcd - rr) * qq;
    return base + idx;
}

// async 16B global->LDS DMA (no VGPR round-trip; tracked by vmcnt)
__device__ __forceinline__ void mgn_cp16(const unsigned short* g, unsigned short* l) {
    __builtin_amdgcn_global_load_lds(
        (const __attribute__((address_space(1))) void*)g,
        (__attribute__((address_space(3))) void*)l, 16, 0, 0);
}
// Stage one 8 KB weight QUARTER (4096 shorts = 8 chunks of 512) with BW waves.
template <int BW>
__device__ __forceinline__ void mgn_stage_q(const unsigned short* __restrict__ src,
                                            unsigned short* wbuf, int tid) {
    const int w = tid >> 6, l = tid & 63;
#pragma unroll
    for (int i = 0; i < 8 / BW; ++i) {
        const int off = (w * (8 / BW) + i) * 512 + l * 8;   // shorts
        mgn_cp16(src + off, wbuf + off);
    }
}

// One weight-quarter of MFMAs: 4 local t-groups x 2 sp, ONE row-tile (M=16),
// full-N acc (8 t-groups live; TQ = 0 or 4 selects which half this quarter
// feeds). ap points at the K-half's A-frag pair. s_setprio keeps the matrix
// pipe fed while other waves stage (T5).
template <int TQ>
__device__ __forceinline__ void mgn_qcompT(const unsigned short* __restrict__ buf, int l,
                                           const mgn_sh8* ap, mgn_f32x4* acc) {
    __builtin_amdgcn_s_setprio(1);
#pragma unroll
    for (int t = 0; t < 4; ++t)
#pragma unroll
        for (int sp = 0; sp < 2; ++sp) {
            mgn_sh8 b = *(const mgn_sh8*)&buf[(t * 2 + sp) * 512 + l * 8];
            acc[TQ + t] = __builtin_amdgcn_mfma_f32_16x16x32_bf16(ap[sp], b, acc[TQ + t], 0, 0, 0);
        }
    __builtin_amdgcn_s_setprio(0);
}

// ---------------------------------------------------------------------------
// flag = 1 -> ij is int32, flag = 0 -> ij is int64
__global__ void mgn_detect_kernel(const int* __restrict__ ij, int* __restrict__ flag) {
    __shared__ int any;
    if (threadIdx.x == 0) any = 0;
    __syncthreads();
    if (ij[2 * threadIdx.x + 1] != 0) atomicOr(&any, 1);
    __syncthreads();
    if (threadIdx.x == 0) *flag = any;
}

__device__ __forceinline__ long mgn_load_idx(const int* __restrict__ ij, long pos, int is32) {
    if (is32) return (long)ij[pos];
    const long long* ij8 = (const long long*)ij;
    return (long)ij8[pos];
}

// ---------------------------------------------------------------------------
// Pack fp32 row-major W[d][k][n] into half-major MFMA B-frag order (r0/r19
// format): i = ((((d*2+sh)*8+t)*2+sp)*64+lane)*8+j holds
//   W[d][(sh*2+sp)*32 + (lane>>4)*8 + j][(lane&15)*8 + t]
// K-half sh is a contiguous 16 KB block; each 8 KB quarter = t-groups {0..3}
// or {4..7} of one K-half, consumed in order Q0(sh0,t03) Q1(sh0,t47)
// Q2(sh1,t03) Q3(sh1,t47) by the full-N schedule.
__global__ void mgn_pack_kernel(const float* __restrict__ W, unsigned short* __restrict__ pw) {
    int i = blockIdx.x * blockDim.x + threadIdx.x;
    if (i >= PWMAT) return;
    int j    = i & 7;
    int lane = (i >> 3) & 63;
    int sp   = (i >> 9) & 1;
    int t    = (i >> 10) & 7;
    int sh   = (i >> 13) & 1;
    int d    = i >> 14;
    int k = (sh * 2 + sp) * 32 + (lane >> 4) * 8 + j;
    int n = (lane & 15) * 8 + t;
    pw[i] = (unsigned short)mgn_bf16bits(W[(d * NDIMC + k) * NDIMC + n]);
}

// ---------------------------------------------------------------------------
// CSR build: histogram -> scan -> fill
__global__ void mgn_deg_kernel(const int* __restrict__ ij, const int* __restrict__ flag,
                               int* __restrict__ deg) {
    int e = blockIdx.x * blockDim.x + threadIdx.x;
    if (e >= NEDGES) return;
    int dst = (int)mgn_load_idx(ij, (long)NEDGES + e, *flag);
    atomicAdd(&deg[dst], 1);
}

__global__ void mgn_scan_kernel(const int* __restrict__ deg,
                                int* __restrict__ rowstart, int* __restrict__ cursor) {
    __shared__ int partial[256];
    const int tid = threadIdx.x;
    const int CH = (NNODES + 255) / 256;   // 196
    const int base = tid * CH;
    int s = 0;
    for (int i = 0; i < CH; ++i) {
        int idx = base + i;
        if (idx < NNODES) s += deg[idx];
    }
    partial[tid] = s;
    __syncthreads();
    for (int off = 1; off < 256; off <<= 1) {
        int add = (tid >= off) ? partial[tid - off] : 0;
        __syncthreads();
        partial[tid] += add;
        __syncthreads();
    }
    int run = (tid == 0) ? 0 : partial[tid - 1];
    for (int i = 0; i < CH; ++i) {
        int idx = base + i;
        if (idx < NNODES) {
            rowstart[idx] = run;
            cursor[idx]   = run;
            run += deg[idx];
        }
    }
    if (tid == 255) rowstart[NNODES] = run;
}

__global__ void mgn_fill_kernel(const int* __restrict__ ij, const int* __restrict__ flag,
                                int* __restrict__ cursor, int* __restrict__ eidx) {
    int e = blockIdx.x * blockDim.x + threadIdx.x;
    if (e >= NEDGES) return;
    int dst = (int)mgn_load_idx(ij, (long)NEDGES + e, *flag);
    int pos = atomicAdd(&cursor[dst], 1);
    eidx[pos] = e;
}

// ---------------------------------------------------------------------------
__global__ void mgn_encoder_kernel(const float* __restrict__ v,
                                   const float* __restrict__ encW,
                                   const float* __restrict__ encB,
                                   float* __restrict__ h) {
    int idx = blockIdx.x * blockDim.x + threadIdx.x;
    if (idx >= NNODES * NDIMC) return;
    int n = idx >> 7, d = idx & 127;
    float acc = encB[d];
#pragma unroll
    for (int k = 0; k < NODEIN; ++k)
        acc = fmaf(v[n * NODEIN + k], encW[k * NDIMC + d], acc);
    h[idx] = acc;
}

__global__ void mgn_decoder_kernel(const float* __restrict__ h,
                                   const float* __restrict__ decW,
                                   const float* __restrict__ decB,
                                   float* __restrict__ out) {
    int idx = blockIdx.x * blockDim.x + threadIdx.x;
    if (idx >= NNODES * NODEIN) return;
    int n = idx / NODEIN, j = idx % NODEIN;
    float acc = decB[j];
#pragma unroll 8
    for (int k = 0; k < NDIMC; ++k)
        acc = fmaf(h[n * NDIMC + k], decW[k * NODEIN + j], acc);
    out[idx] = acc;
}

// ---------------------------------------------------------------------------
// Fused 6-deep residual MLP, bf16 MFMA core, fp32 residual/LN.
// r23: OCCUPANCY 3->4 blocks/CU. r22 post-mortem: prediction matched (3002us,
// no spills); kernel is latency-bound at 12 waves/CU (VALU 56%, LDS ~30%,
// nothing saturated); occupancy limiter is LDS (51.2 KB -> 3 blocks).
// Change: M=16/wave + FULL-N acc (8 t-groups, r19 packing/schedule):
//   - LDS = 17408 (xl, 64 rows) + 16384 (wq ping-pong) = 33.8 KB -> 4 blocks
//     = 16 waves/CU (+33% latency hiding)
//   - live regs ~110 <= 128 (cap for 4 waves/SIMD, __launch_bounds__(256,4)):
//     xres 32 + acc 32 + a 16 + temps. M=16 is what makes full-N affordable.
//   - full-N removes the N-split h2-nh0 stash/reload and halves h1-stash
//     events (LN reads acc directly) -> VALU/row down ~15 ops
//   - cost: B-LDS reads/row double (B feeds 16 rows not 32) -> LDS ~50% busy
// Kept from r22: DPP LN reduce, s_setprio around MFMA, XCD block swizzle,
// 8 KB quarter ping-pong, 8 phases/depth.
// Spill tripwire: WRITE_SIZE >> 300 MB means the 128-reg cap failed; revert.
template <int MODE, int BW>
__global__ __launch_bounds__(BW * 64, 4) void mgn_mlp6_mfma_kernel(
    float* __restrict__ Xf,               // node: h
    unsigned short* __restrict__ Eb,      // e buffer (CSR-slot order)
    const float* __restrict__ H,          // edge: h for gather
    const int* __restrict__ ij,
    const int* __restrict__ flag,
    const int* __restrict__ rowstart,     // node CSR
    const int* __restrict__ eidx,         // edge: slot -> original edge id
    int addE, int nrows,
    const unsigned short* __restrict__ PW1,
    const unsigned short* __restrict__ PW2,
    const float* __restrict__ B1, const float* __restrict__ B2,
    const float* __restrict__ G,  const float* __restrict__ BT)
{
    __shared__ unsigned short xl[BW * 16 * 136];   // x/h1 tile, row stride 136 (17408 B)
    __shared__ unsigned short wqA[4096];           // weight quarter ping (8 KB)
    __shared__ unsigned short wqB[4096];           // weight quarter pong (8 KB)
    const int tid = threadIdx.x;
    const int w   = tid >> 6;
    const int l   = tid & 63;
    const int q   = l >> 4;
    const int lm  = l & 15;
    const int ct  = lm * 8;                        // first of lane's 8 cols
    const int wbase = w * 16;                      // wave's first local row
    const int bid = mgn_swz((int)blockIdx.x, (int)gridDim.x);
    const long rowbase = (long)bid * (16 * BW);

    const int is32 = (MODE == 1) ? *flag : 0;

    // pre-stage depth-0 W1 quarter 0 -> wqA; drains at first barrier
    mgn_stage_q<BW>(PW1, wqA, tid);

    // ---- tile load: xres fp32 regs (C layout) + LDS bf16 (A source)
    float xres[4][8];
#pragma unroll
    for (int r = 0; r < 4; ++r) {
        const int rloc = wbase + q * 4 + r;
        long gr = rowbase + rloc;
        bool ok = gr < nrows;
        float xv[8];
#pragma unroll
        for (int t = 0; t < 8; ++t) xv[t] = 0.f;
        if (MODE == 1) {
            if (ok) {
                long er = (long)eidx[gr];     // original edge id for this slot
                long i0 = mgn_load_idx(ij, er, is32);
                long i1 = mgn_load_idx(ij, (long)NEDGES + er, is32);
                const float* p0 = H + i0 * NDIMC + ct;
                const float* p1 = H + i1 * NDIMC + ct;
                float4 a0 = *(const float4*)p0, a1 = *(const float4*)(p0 + 4);
                float4 b0 = *(const float4*)p1, b1 = *(const float4*)(p1 + 4);
                xv[0] = a0.x - b0.x; xv[1] = a0.y - b0.y;
                xv[2] = a0.z - b0.z; xv[3] = a0.w - b0.w;
                xv[4] = a1.x - b1.x; xv[5] = a1.y - b1.y;
                xv[6] = a1.z - b1.z; xv[7] = a1.w - b1.w;
                if (addE) {
                    uint4 u4 = *(const uint4*)(Eb + (size_t)gr * NDIMC + ct);
                    xv[0] += __uint_as_float(u4.x << 16);
                    xv[1] += __uint_as_float(u4.x & 0xffff0000u);
                    xv[2] += __uint_as_float(u4.y << 16);
                    xv[3] += __uint_as_float(u4.y & 0xffff0000u);
                    xv[4] += __uint_as_float(u4.z << 16);
                    xv[5] += __uint_as_float(u4.z & 0xffff0000u);
                    xv[6] += __uint_as_float(u4.w << 16);
                    xv[7] += __uint_as_float(u4.w & 0xffff0000u);
                }
            }
        } else {
            if (ok) {
                float4 a0 = *(const float4*)(Xf + gr * NDIMC + ct);
                float4 a1 = *(const float4*)(Xf + gr * NDIMC + ct + 4);
                xv[0] = a0.x; xv[1] = a0.y; xv[2] = a0.z; xv[3] = a0.w;
                xv[4] = a1.x; xv[5] = a1.y; xv[6] = a1.z; xv[7] = a1.w;
                // CSR aggregate: CONTIGUOUS slot range (no indirection)
                int rs = rowstart[gr], re = rowstart[gr + 1];
                for (int k = rs; k < re; ++k) {
                    uint4 u4 = *(const uint4*)(Eb + (size_t)k * NDIMC + ct);
                    xv[0] += __uint_as_float(u4.x << 16);
                    xv[1] += __uint_as_float(u4.x & 0xffff0000u);
                    xv[2] += __uint_as_float(u4.y << 16);
                    xv[3] += __uint_as_float(u4.y & 0xffff0000u);
                    xv[4] += __uint_as_float(u4.z << 16);
                    xv[5] += __uint_as_float(u4.z & 0xffff0000u);
                    xv[6] += __uint_as_float(u4.w << 16);
                    xv[7] += __uint_as_float(u4.w & 0xffff0000u);
                }
            }
        }
#pragma unroll
        for (int t = 0; t < 8; ++t) xres[r][t] = xv[t];
        uint4 pk;
        pk.x = mgn_pk(xv[0], xv[1]); pk.y = mgn_pk(xv[2], xv[3]);
        pk.z = mgn_pk(xv[4], xv[5]); pk.w = mgn_pk(xv[6], xv[7]);
        *(uint4*)&xl[rloc * 136 + ct] = pk;
    }

    __syncthreads();   // depth-0 Q0 visible in wqA

    mgn_sh8 a[4];                  // A frags (full K) for the wave's row-tile
    mgn_f32x4 acc[8];              // full-N accumulators (8 t-groups)
    const int arow = (wbase + lm) * 136;

    for (int d = 0; d < DEPTHC; ++d) {
        const unsigned short* pw1 = PW1 + (size_t)d * 16384;
        const unsigned short* pw2 = PW2 + (size_t)d * 16384;

        // ---- A1 frags (x, full K) + acc init with b1
#pragma unroll
        for (int s = 0; s < 4; ++s)
            a[s] = *(const mgn_sh8*)&xl[arow + s * 32 + q * 8];
        {
            float4 ba = *(const float4*)(B1 + d * NDIMC + ct);
            float4 bb = *(const float4*)(B1 + d * NDIMC + ct + 4);
            float bv[8] = {ba.x, ba.y, ba.z, ba.w, bb.x, bb.y, bb.z, bb.w};
#pragma unroll
            for (int t = 0; t < 8; ++t)
                acc[t] = (mgn_f32x4){bv[t], bv[t], bv[t], bv[t]};
        }

        // ---- ph0: stage Q1->B | Q0 (sh0,t03) from A
        mgn_stage_q<BW>(pw1 + 4096, wqB, tid);
        mgn_qcompT<0>(wqA, l, a + 0, acc);
        __syncthreads();
        // ---- ph1: stage Q2->A | Q1 (sh0,t47) from B
        mgn_stage_q<BW>(pw1 + 8192, wqA, tid);
        mgn_qcompT<4>(wqB, l, a + 0, acc);
        __syncthreads();
        // ---- ph2: stage Q3->B | Q2 (sh1,t03) from A
        mgn_stage_q<BW>(pw1 + 12288, wqB, tid);
        mgn_qcompT<0>(wqA, l, a + 2, acc);
        __syncthreads();
        // ---- ph3: stage W2 Q0->A | Q3 (sh1,t47) from B; h1 epilogue; A2; b2
        mgn_stage_q<BW>(pw2, wqA, tid);
        mgn_qcompT<4>(wqB, l, a + 2, acc);
#pragma unroll
        for (int r = 0; r < 4; ++r) {
            const int rloc = wbase + q * 4 + r;
            float h1[8];
#pragma unroll
            for (int t = 0; t < 8; ++t) h1[t] = fmaxf(acc[t][r], 0.f);
            uint4 pk;
            pk.x = mgn_pk(h1[0], h1[1]); pk.y = mgn_pk(h1[2], h1[3]);
            pk.z = mgn_pk(h1[4], h1[5]); pk.w = mgn_pk(h1[6], h1[7]);
            *(uint4*)&xl[rloc * 136 + ct] = pk;
        }
        // A2 frags (h1, full K) — xl rows are wave-private, in-wave ordering
#pragma unroll
        for (int s = 0; s < 4; ++s)
            a[s] = *(const mgn_sh8*)&xl[arow + s * 32 + q * 8];
        {
            float4 ba = *(const float4*)(B2 + d * NDIMC + ct);
            float4 bb = *(const float4*)(B2 + d * NDIMC + ct + 4);
            float bv[8] = {ba.x, ba.y, ba.z, ba.w, bb.x, bb.y, bb.z, bb.w};
#pragma unroll
            for (int t = 0; t < 8; ++t)
                acc[t] = (mgn_f32x4){bv[t], bv[t], bv[t], bv[t]};
        }
        __syncthreads();
        // ---- ph4: stage W2 Q1->B | W2 Q0 (sh0,t03) from A
        mgn_stage_q<BW>(pw2 + 4096, wqB, tid);
        mgn_qcompT<0>(wqA, l, a + 0, acc);
        __syncthreads();
        // ---- ph5: stage W2 Q2->A | W2 Q1 (sh0,t47) from B
        mgn_stage_q<BW>(pw2 + 8192, wqA, tid);
        mgn_qcompT<4>(wqB, l, a + 0, acc);
        __syncthreads();
        // ---- ph6: stage W2 Q3->B | W2 Q2 (sh1,t03) from A
        mgn_stage_q<BW>(pw2 + 12288, wqB, tid);
        mgn_qcompT<0>(wqA, l, a + 2, acc);
        __syncthreads();
        // ---- ph7: stage next-depth W1 Q0->A | W2 Q3 (sh1,t47) from B; LN epi
        if (d + 1 < DEPTHC)
            mgn_stage_q<BW>(PW1 + (size_t)(d + 1) * 16384, wqA, tid);
        mgn_qcompT<4>(wqB, l, a + 2, acc);

        {
            float4 ga  = *(const float4*)(G  + d * NDIMC + ct);
            float4 gb  = *(const float4*)(G  + d * NDIMC + ct + 4);
            float4 bta = *(const float4*)(BT + d * NDIMC + ct);
            float4 btb = *(const float4*)(BT + d * NDIMC + ct + 4);
            float gv[8]  = {ga.x, ga.y, ga.z, ga.w, gb.x, gb.y, gb.z, gb.w};
            float btv[8] = {bta.x, bta.y, bta.z, bta.w, btb.x, btb.y, btb.z, btb.w};
#pragma unroll
            for (int r = 0; r < 4; ++r) {
                const int rloc = wbase + q * 4 + r;
                float h2[8];
#pragma unroll
                for (int t = 0; t < 8; ++t) h2[t] = fmaxf(acc[t][r], 0.f);
                // single-pass sum & sumsq; xor1/xor2 via DPP quads, xor4 via
                // shuffle, xor8 via DPP row_ror:8 (within the 16-lane group)
                float sum = 0.f, ssq = 0.f;
#pragma unroll
                for (int t = 0; t < 8; ++t) {
                    sum += h2[t];
                    ssq = fmaf(h2[t], h2[t], ssq);
                }
                sum = mgn_dppadd<0xB1>(sum);  ssq = mgn_dppadd<0xB1>(ssq);
                sum = mgn_dppadd<0x4E>(sum);  ssq = mgn_dppadd<0x4E>(ssq);
                sum += __shfl_xor(sum, 4);    ssq += __shfl_xor(ssq, 4);
                sum = mgn_dppadd<0x128>(sum); ssq = mgn_dppadd<0x128>(ssq);
                float mean = sum * 0.0078125f;
                float var  = fmaf(-mean, mean, ssq * 0.0078125f);
                float rstd = rsqrtf(var + LNEPS);
#pragma unroll
                for (int t = 0; t < 8; ++t) {
                    float at = rstd * gv[t];
                    float ctt = fmaf(-mean, at, btv[t]);
                    xres[r][t] += fmaf(h2[t], at, ctt);
                }
                if (d != DEPTHC - 1) {
                    uint4 pk;
                    pk.x = mgn_pk(xres[r][0], xres[r][1]);
                    pk.y = mgn_pk(xres[r][2], xres[r][3]);
                    pk.z = mgn_pk(xres[r][4], xres[r][5]);
                    pk.w = mgn_pk(xres[r][6], xres[r][7]);
                    *(uint4*)&xl[rloc * 136 + ct] = pk;
                }
            }
        }
        if (d + 1 < DEPTHC) __syncthreads();   // next-depth Q0 visible in wqA
    }

    // ---- tile store
#pragma unroll
    for (int r = 0; r < 4; ++r) {
        const int rloc = wbase + q * 4 + r;
        long gr = rowbase + rloc;
        if (gr < nrows) {
            if (MODE == 1) {
                uint4 pk;
                pk.x = mgn_pk(xres[r][0], xres[r][1]);
                pk.y = mgn_pk(xres[r][2], xres[r][3]);
                pk.z = mgn_pk(xres[r][4], xres[r][5]);
                pk.w = mgn_pk(xres[r][6], xres[r][7]);
                *(uint4*)(Eb + (size_t)gr * NDIMC + ct) = pk;
            } else {
                float4 o0 = {xres[r][0], xres[r][1], xres[r][2], xres[r][3]};
                float4 o1 = {xres[r][4], xres[r][5], xres[r][6], xres[r][7]};
                *(float4*)(Xf + gr * NDIMC + ct)     = o0;
                *(float4*)(Xf + gr * NDIMC + ct + 4) = o1;
            }
        }
    }
}

// ---------------------------------------------------------------------------
extern "C" void kernel_launch(void* const* d_in, const int* in_sizes, int n_in,
                              void* d_out, int out_size, void* d_ws, size_t ws_size,
                              hipStream_t stream) {
    const float* v    = (const float*)d_in[0];
    const int*   ij   = (const int*)d_in[1];
    const float* encW = (const float*)d_in[2];
    const float* encB = (const float*)d_in[3];
    const float* eW1  = (const float*)d_in[4];
    const float* eB1  = (const float*)d_in[5];
    const float* eW2  = (const float*)d_in[6];
    const float* eB2  = (const float*)d_in[7];
    const float* eG   = (const float*)d_in[8];
    const float* eBT  = (const float*)d_in[9];
    const float* nW1  = (const float*)d_in[10];
    const float* nB1  = (const float*)d_in[11];
    const float* nW2  = (const float*)d_in[12];
    const float* nB2  = (const float*)d_in[13];
    const float* nG   = (const float*)d_in[14];
    const float* nBT  = (const float*)d_in[15];
    const float* decW = (const float*)d_in[16];
    const float* decB = (const float*)d_in[17];
    float* out = (float*)d_out;

    char* ws = (char*)d_ws;
    float*          h    = (float*)(ws + H_OFF);
    unsigned short* ebuf = (unsigned short*)(ws + E_OFF);
    unsigned short* pw   = (unsigned short*)(ws + PW_OFF);
    int*            flag = (int*)(ws + FLAG_OFF);
    int*            deg  = (int*)(ws + DEG_OFF);
    int*            rstt = (int*)(ws + RS_OFF);
    int*            curs = (int*)(ws + CUR_OFF);
    int*            eidx = (int*)(ws + EIDX_OFF);

    mgn_detect_kernel<<<1, 256, 0, stream>>>(ij, flag);
    mgn_pack_kernel<<<(PWMAT + 255) / 256, 256, 0, stream>>>(eW1, pw + 0 * PWMAT);
    mgn_pack_kernel<<<(PWMAT + 255) / 256, 256, 0, stream>>>(eW2, pw + 1 * PWMAT);
    mgn_pack_kernel<<<(PWMAT + 255) / 256, 256, 0, stream>>>(nW1, pw + 2 * PWMAT);
    mgn_pack_kernel<<<(PWMAT + 255) / 256, 256, 0, stream>>>(nW2, pw + 3 * PWMAT);

    // CSR build (static graph; rebuilt every call for graph-capture safety)
    hipMemsetAsync(deg, 0, (size_t)(NNODES + 1) * sizeof(int), stream);
    mgn_deg_kernel<<<(NEDGES + 255) / 256, 256, 0, stream>>>(ij, flag, deg);
    mgn_scan_kernel<<<1, 256, 0, stream>>>(deg, rstt, curs);
    mgn_fill_kernel<<<(NEDGES + 255) / 256, 256, 0, stream>>>(ij, flag, curs, eidx);

    mgn_encoder_kernel<<<(NNODES * NDIMC + 255) / 256, 256, 0, stream>>>(v, encW, encB, h);

    for (int p = 0; p < NPASSESC; ++p) {
        // edge MLP (fused gather; e in CSR-slot order; 64 rows/block)
        mgn_mlp6_mfma_kernel<1, 4><<<NEDGES / 64, 256, 0, stream>>>(
            nullptr, ebuf, h, ij, flag, nullptr, eidx, p > 0 ? 1 : 0, NEDGES,
            pw + 0 * PWMAT, pw + 1 * PWMAT, eB1, eB2, eG, eBT);
        // node MLP with fused CSR aggregation (contiguous Eb reads; 64 rows/block)
        mgn_mlp6_mfma_kernel<0, 4><<<(NNODES + 63) / 64, 256, 0, stream>>>(
            h, ebuf, nullptr, nullptr, nullptr, rstt, nullptr, 0, NNODES,
            pw + 2 * PWMAT, pw + 3 * PWMAT, nB1, nB2, nG, nBT);
    }

    mgn_decoder_kernel<<<(NNODES * NODEIN + 255) / 256, 256, 0, stream>>>(h, decW, decB, out);
}